// Round 3
// baseline (991.751 us; speedup 1.0000x reference)
//
#include <hip/hip_runtime.h>
#include <hip/hip_bf16.h>
#include <stdint.h>

#define LVL 24
#define NN  8192
#define DIN 256
#define DD  128
#define BM  32
#define LDSW (DIN + 8)   // padded LDS row (ushorts): 528B stride, 16B-aligned

typedef __attribute__((ext_vector_type(8))) short bf16x8;
typedef __attribute__((ext_vector_type(4))) float f32x4;

__device__ __forceinline__ float b2f(unsigned short u) {
    union { unsigned int i; float f; } v; v.i = ((unsigned int)u) << 16; return v.f;
}
__device__ __forceinline__ unsigned short f2b(float f) {
    union { float f; unsigned int i; } v; v.f = f;
    unsigned int x = v.i;
    return (unsigned short)((x + 0x7fffu + ((x >> 16) & 1u)) >> 16);  // RNE
}
__device__ __forceinline__ float sig_(float x) { return 1.0f / (1.0f + __expf(-x)); }

__device__ __forceinline__ float ldf(const void* p, size_t i, int isf) {
    return isf ? ((const float*)p)[i] : b2f(((const unsigned short*)p)[i]);
}

// ---------------- dtype detector ----------------
// bf16 array: even-indexed ushorts are genuine N(0,1) bf16 (exp field ~[110,130]).
// fp32 array: even-indexed ushorts are fp32 low-mantissa bits (uniform exp field).
__global__ void detect_kernel(const unsigned short* __restrict__ t, int* __restrict__ flag) {
    __shared__ int cnt;
    if (threadIdx.x == 0) cnt = 0;
    __syncthreads();
    int bad = 0;
    #pragma unroll
    for (int r = 0; r < 4; ++r) {
        unsigned short u = t[(threadIdx.x * 4 + r) * 2];
        int e = (u >> 7) & 255;
        bad += (e >= 136 || (e >= 1 && e <= 90)) ? 1 : 0;
    }
    atomicAdd(&cnt, bad);
    __syncthreads();
    if (threadIdx.x == 0) *flag = (cnt > 16) ? 1 : 0;
}

// ---------------- weight/bias/init conversion into ws ----------------
// Wcat rows: [0,512)=W_w(f,i,u,o); [512,640)=U_f1; [640,768)=U_f2; [768,1152)=U_iuo(i,u,o)
__global__ __launch_bounds__(256)
void convert_kernel(const void* Ww, const void* Wb, const void* Uf1, const void* Uf2,
                    const void* Uiuo, const void* hini, const void* cini,
                    unsigned short* __restrict__ wcat, float* __restrict__ bias,
                    unsigned short* __restrict__ hinit_b, float* __restrict__ cinit_f,
                    const int* __restrict__ flag) {
    const int isf = *flag;
    const int bid = blockIdx.x;
    const int t = threadIdx.x;
    if (bid < 1152) {
        const int row = bid, col = t;
        float v;
        if (row < 512)       v = ldf(Ww,   (size_t)row * DIN + col, isf);
        else if (row < 640)  v = ldf(Uf1,  (size_t)(row - 512) * DIN + col, isf);
        else if (row < 768)  v = ldf(Uf2,  (size_t)(row - 640) * DIN + col, isf);
        else                 v = ldf(Uiuo, (size_t)(row - 768) * DIN + col, isf);
        wcat[(size_t)row * DIN + col] = f2b(v);
    } else if (bid == 1152) {
        bias[t] = ldf(Wb, t, isf);
    } else if (bid == 1153) {
        bias[256 + t] = ldf(Wb, 256 + t, isf);
    } else {
        if (t < 128) hinit_b[t] = f2b(ldf(hini, t, isf));
        else if (t < 256) cinit_f[t - 128] = ldf(cini, t - 128, isf);
    }
}

// ---------------- one tree level: fused dual-GEMM + LSTM pointwise ----------------
// grid (NN/BM, 2), block 256 (4 waves). Wave w handles d-range [blockIdx.y*64 + w*16, +16).
__global__ __launch_bounds__(256)
void level_kernel(const void* __restrict__ xbase,        // [L,NN,DIN] fp32 or bf16 (full tensor)
                  int level,
                  const int* __restrict__ idx,           // [NN, 2] this level
                  const unsigned short* __restrict__ hprev, // [NN, DD] bf16 state (prev level)
                  const float* __restrict__ cprev,       // [NN, DD] fp32 state
                  unsigned short* __restrict__ hnew,     // [NN, DD] bf16 state out
                  float* __restrict__ cnew,              // [NN, DD] fp32 state out
                  float* __restrict__ outh,              // [NN, DD] fp32 -> d_out
                  float* __restrict__ outc,              // [NN, DD] fp32 -> d_out
                  const unsigned short* __restrict__ wcat,
                  const float* __restrict__ bias,
                  const unsigned short* __restrict__ hinit_b,
                  const float* __restrict__ cinit_f,
                  const int* __restrict__ flag,
                  int first) {
    __shared__ unsigned short xa[BM][LDSW];
    __shared__ unsigned short ha[BM][LDSW];

    const int tid = threadIdx.x;
    const int isf = *flag;

    // ---- stage x tile: 8 threads/row, 32 cols each ----
    {
        const int r = tid >> 3;
        const int cb = (tid & 7) * 32;
        const size_t row_elem = (size_t)level * NN * DIN + (size_t)(blockIdx.x * BM + r) * DIN;
        if (isf) {
            const float4* xr = (const float4*)((const float*)xbase + row_elem);
            #pragma unroll
            for (int j = 0; j < 8; ++j) {
                float4 v = xr[cb / 4 + j];
                ushort4 p; p.x = f2b(v.x); p.y = f2b(v.y); p.z = f2b(v.z); p.w = f2b(v.w);
                *(ushort4*)&xa[r][cb + 4 * j] = p;
            }
        } else {
            const uint4* xr = (const uint4*)((const unsigned short*)xbase + row_elem);
            #pragma unroll
            for (int j = 0; j < 4; ++j) {
                *(uint4*)&xa[r][cb + 8 * j] = xr[cb / 8 + j];
            }
        }
    }

    // ---- gather children h (bf16): 4 threads per (row, child), 32 cols each ----
    {
        const int slot = tid >> 2;
        const int r = slot >> 1;
        const int s = slot & 1;
        const int part = tid & 3;
        const int node = blockIdx.x * BM + r;
        const int ai = idx[node * 2 + s];
        const unsigned short* src = (first || ai < 0)
            ? (hinit_b + part * 32)
            : (hprev + (size_t)ai * DD + part * 32);
        const uint4* s4 = (const uint4*)src;
        uint4* dst = (uint4*)&ha[r][s * DD + part * 32];
        dst[0] = s4[0]; dst[1] = s4[1]; dst[2] = s4[2]; dst[3] = s4[3];
    }
    __syncthreads();

    // ---- MFMA: 9 gate tiles x 2 m-tiles, K=256 in 8 steps ----
    const int lane = tid & 63;
    const int wave = tid >> 6;
    const int m = lane & 15;
    const int q = lane >> 4;
    const int d0 = blockIdx.y * 64 + wave * 16;

    const bf16x8* bp[9];
    {
        const int rb[9] = { d0 + m, 128 + d0 + m, 256 + d0 + m, 384 + d0 + m,
                            512 + d0 + m, 640 + d0 + m,
                            768 + d0 + m, 896 + d0 + m, 1024 + d0 + m };
        #pragma unroll
        for (int g = 0; g < 9; ++g) bp[g] = (const bf16x8*)(wcat + (size_t)rb[g] * DIN);
    }

    f32x4 acc[9][2];
    #pragma unroll
    for (int g = 0; g < 9; ++g) { acc[g][0] = (f32x4)0.0f; acc[g][1] = (f32x4)0.0f; }

    #pragma unroll
    for (int kk = 0; kk < 8; ++kk) {
        const int k0 = kk * 32 + q * 8;
        bf16x8 a0 = *(const bf16x8*)&xa[m][k0];
        bf16x8 a1 = *(const bf16x8*)&xa[16 + m][k0];
        bf16x8 h0 = *(const bf16x8*)&ha[m][k0];
        bf16x8 h1 = *(const bf16x8*)&ha[16 + m][k0];
        #pragma unroll
        for (int g = 0; g < 4; ++g) {
            bf16x8 b = bp[g][kk * 4 + q];
            acc[g][0] = __builtin_amdgcn_mfma_f32_16x16x32_bf16(a0, b, acc[g][0], 0, 0, 0);
            acc[g][1] = __builtin_amdgcn_mfma_f32_16x16x32_bf16(a1, b, acc[g][1], 0, 0, 0);
        }
        #pragma unroll
        for (int g = 4; g < 9; ++g) {
            bf16x8 b = bp[g][kk * 4 + q];
            acc[g][0] = __builtin_amdgcn_mfma_f32_16x16x32_bf16(h0, b, acc[g][0], 0, 0, 0);
            acc[g][1] = __builtin_amdgcn_mfma_f32_16x16x32_bf16(h1, b, acc[g][1], 0, 0, 0);
        }
    }

    // ---- pointwise LSTM: C layout col=lane&15, row=q*4+reg -> purely per-lane ----
    const int d = d0 + m;
    const float bf = bias[d], bi = bias[128 + d], bu = bias[256 + d], bo = bias[384 + d];
    #pragma unroll
    for (int mt = 0; mt < 2; ++mt) {
        const int rowb = blockIdx.x * BM + mt * 16 + q * 4;
        #pragma unroll
        for (int j = 0; j < 4; ++j) {
            const int nd = rowb + j;
            const int a  = idx[nd * 2 + 0];
            const int b_ = idx[nd * 2 + 1];
            const float ca = (first || a  < 0) ? cinit_f[d] : cprev[(size_t)a  * DD + d];
            const float cb = (first || b_ < 0) ? cinit_f[d] : cprev[(size_t)b_ * DD + d];
            const float fx = acc[0][mt][j] + bf;
            const float ix = acc[1][mt][j] + bi;
            const float ux = acc[2][mt][j] + bu;
            const float ox = acc[3][mt][j] + bo;
            const float f1 = sig_(fx + acc[4][mt][j]);
            const float f2 = sig_(fx + acc[5][mt][j]);
            const float ig = sig_(ix + acc[6][mt][j]);
            const float ug = tanhf(ux + acc[7][mt][j]);
            const float og = sig_(ox + acc[8][mt][j]);
            const float nc = ig * ug + f1 * ca + f2 * cb;
            const float nh = og * tanhf(nc);
            const size_t o = (size_t)nd * DD + d;
            hnew[o] = f2b(nh);
            cnew[o] = nc;
            outh[o] = nh;
            outc[o] = nc;
        }
    }
}

extern "C" void kernel_launch(void* const* d_in, const int* in_sizes, int n_in,
                              void* d_out, int out_size, void* d_ws, size_t ws_size,
                              hipStream_t stream) {
    const void* tensor  = d_in[0];
    const int*  indices = (const int*)d_in[1];
    const void* h_init  = d_in[2];
    const void* c_init  = d_in[3];
    const void* Ww      = d_in[4];
    const void* Wb      = d_in[5];
    const void* Uf1     = d_in[6];
    const void* Uf2     = d_in[7];
    const void* Uiuo    = d_in[8];
    float* out = (float*)d_out;   // fp32: [h(L,N,D) | c(L,N,D)]

    char* wsb = (char*)d_ws;
    int* flag                = (int*)wsb;                               // @0
    unsigned short* wcat     = (unsigned short*)(wsb + 256);            // 589,824 B
    float* bias              = (float*)(wsb + 590336);                  // 2 KB
    unsigned short* hinit_b  = (unsigned short*)(wsb + 592640);         // 256 B
    float* cinit_f           = (float*)(wsb + 593152);                  // 512 B
    float* c0                = (float*)(wsb + (1u << 20));              // 4 MB
    float* c1                = (float*)(wsb + (1u << 20) + 4194304);    // 4 MB
    unsigned short* h0       = (unsigned short*)(wsb + (1u << 20) + 8388608);   // 2 MB
    unsigned short* h1       = (unsigned short*)(wsb + (1u << 20) + 10485760);  // 2 MB

    detect_kernel<<<1, 64, 0, stream>>>((const unsigned short*)tensor, flag);
    convert_kernel<<<1155, 256, 0, stream>>>(Ww, Wb, Uf1, Uf2, Uiuo, h_init, c_init,
                                             wcat, bias, hinit_b, cinit_f, flag);

    float* cp = c0; float* cn = c1;
    unsigned short* hp = h0; unsigned short* hn = h1;
    for (int l = 0; l < LVL; ++l) {
        dim3 grid(NN / BM, 2);
        level_kernel<<<grid, 256, 0, stream>>>(
            tensor, l,
            indices + (size_t)l * NN * 2,
            hp, cp, hn, cn,
            out + (size_t)l * NN * DD,
            out + (size_t)(LVL + l) * NN * DD,
            wcat, bias, hinit_b, cinit_f, flag, (l == 0) ? 1 : 0);
        float* tc = cp; cp = cn; cn = tc;
        unsigned short* th = hp; hp = hn; hn = th;
    }
}